// Round 2
// baseline (5512.860 us; speedup 1.0000x reference)
//
#include <hip/hip_runtime.h>
#include <math.h>

#define TSTEPS 12
#define BATCH  2048
#define IMG    512
#define HIDN   1024
#define NCLASS 51
#define SCALE_X 1.7320508075688772f      // sqrt(1 + 2*e^0) = sqrt(3)

// ---------------------------------------------------------------------------
// fp32 tiled GEMM: C[M,N] = A[M,K] * B[K,N], all row-major.
// BM=BN=128, BK=16, 256 threads, 8x8 micro-tile per thread.
// M, N, K must be multiples of 128/128/16 (true for all our shapes).
// ---------------------------------------------------------------------------
__global__ __launch_bounds__(256)
void gemm_f32(const float* __restrict__ A, const float* __restrict__ B,
              float* __restrict__ C, int N, int K) {
    constexpr int BM = 128, BN = 128, BK = 16, TM = 8, TN = 8;
    __shared__ float As[BK][BM + 4];   // row = 132 floats = 528 B (16B-multiple)
    __shared__ float Bs[BK][BN];

    const int tid = threadIdx.x;
    const int bn  = blockIdx.x * BN;
    const int bm  = blockIdx.y * BM;
    const int tx  = tid & 15;          // 16 threads along N
    const int ty  = tid >> 4;          // 16 threads along M

    const int arow = tid >> 2;         // 64 rows per pass
    const int acol = (tid & 3) << 2;   // 4 floats along K
    const int brow = tid >> 5;         // 8 rows per pass
    const int bcol = (tid & 31) << 2;  // 4 floats along N

    float acc[TM][TN] = {};

    for (int k0 = 0; k0 < K; k0 += BK) {
        #pragma unroll
        for (int r = 0; r < BM; r += 64) {
            float4 v = *(const float4*)(A + (size_t)(bm + arow + r) * K + k0 + acol);
            As[acol + 0][arow + r] = v.x;
            As[acol + 1][arow + r] = v.y;
            As[acol + 2][arow + r] = v.z;
            As[acol + 3][arow + r] = v.w;
        }
        #pragma unroll
        for (int r = 0; r < BK; r += 8) {
            float4 v = *(const float4*)(B + (size_t)(k0 + brow + r) * N + bn + bcol);
            *(float4*)&Bs[brow + r][bcol] = v;
        }
        __syncthreads();

        #pragma unroll
        for (int kk = 0; kk < BK; ++kk) {
            float a[TM], b[TN];
            *(float4*)&a[0] = *(const float4*)&As[kk][ty * TM];
            *(float4*)&a[4] = *(const float4*)&As[kk][ty * TM + 4];
            *(float4*)&b[0] = *(const float4*)&Bs[kk][tx * TN];
            *(float4*)&b[4] = *(const float4*)&Bs[kk][tx * TN + 4];
            #pragma unroll
            for (int i = 0; i < TM; ++i)
                #pragma unroll
                for (int j = 0; j < TN; ++j)
                    acc[i][j] = fmaf(a[i], b[j], acc[i][j]);
        }
        __syncthreads();
    }

    #pragma unroll
    for (int i = 0; i < TM; ++i) {
        float* crow = C + (size_t)(bm + ty * TM + i) * N + bn + tx * TN;
        *(float4*)(crow)     = make_float4(acc[i][0], acc[i][1], acc[i][2], acc[i][3]);
        *(float4*)(crow + 4) = make_float4(acc[i][4], acc[i][5], acc[i][6], acc[i][7]);
    }
}

// ---------------------------------------------------------------------------
// SRU recurrence over T=12 for one batch chunk. One thread per (b_local, h).
// U rows ordered (b_local, t), row stride = ustride; u0/u1/u2 at col 0/H/2H.
// resid: separate pointer + stride (layer0: U+3H, stride 4H; else prev h).
// Optionally writes hbar[b_local,h] = mean_t h.
// ---------------------------------------------------------------------------
__global__ __launch_bounds__(256)
void sru_recur(const float* __restrict__ U, const float* __restrict__ resid,
               const float* __restrict__ vc, const float* __restrict__ bias,
               float* __restrict__ hout, float* __restrict__ hbar,
               int ustride, int rstride) {
    const int idx = blockIdx.x * 256 + threadIdx.x;   // [0, CB*HIDN)
    const int b = idx >> 10;                          // local batch
    const int h = idx & (HIDN - 1);

    const float vf = vc[h],  vr = vc[HIDN + h];
    const float bf = bias[h], br = bias[HIDN + h];

    float c = 0.f, sum = 0.f;
    size_t urow = (size_t)b * TSTEPS * ustride + h;
    size_t rrow = (size_t)b * TSTEPS * rstride + h;
    size_t orow = (size_t)b * TSTEPS * HIDN   + h;

    #pragma unroll
    for (int t = 0; t < TSTEPS; ++t) {
        const float u0 = U[urow];
        const float u1 = U[urow + HIDN];
        const float u2 = U[urow + 2 * HIDN];
        const float xt = resid[rrow];

        const float f = 1.f / (1.f + __expf(-(u1 + vf * c + bf)));
        c = f * c + (1.f - f) * u0;
        const float r = 1.f / (1.f + __expf(-(u2 + vr * c + br)));
        const float hv = r * tanhf(c) + (1.f - r) * xt * SCALE_X;

        hout[orow] = hv;
        sum += hv;
        urow += ustride; rrow += rstride; orow += HIDN;
    }
    if (hbar) hbar[(size_t)b * HIDN + h] = sum * (1.f / TSTEPS);
}

// ---------------------------------------------------------------------------
// Final FC on time-averaged h: out[b,c] = hbar[b,:] . fc_w[:,c] + fc_b[c]
// One 64-thread block per local batch; hbar row staged in LDS.
// ---------------------------------------------------------------------------
__global__ __launch_bounds__(64)
void final_fc(const float* __restrict__ hbar, const float* __restrict__ fcw,
              const float* __restrict__ fcb, float* __restrict__ out) {
    __shared__ float hrow[HIDN];
    const int b = blockIdx.x;
    for (int i = threadIdx.x; i < HIDN; i += 64)
        hrow[i] = hbar[(size_t)b * HIDN + i];
    __syncthreads();

    const int c = threadIdx.x;
    if (c < NCLASS) {
        float acc = fcb[c];
        #pragma unroll 8
        for (int k = 0; k < HIDN; ++k)
            acc = fmaf(hrow[k], fcw[(size_t)k * NCLASS + c], acc);
        out[(size_t)b * NCLASS + c] = acc;
    }
}

// ---------------------------------------------------------------------------
extern "C" void kernel_launch(void* const* d_in, const int* in_sizes, int n_in,
                              void* d_out, int out_size, void* d_ws, size_t ws_size,
                              hipStream_t stream) {
    const float* x   = (const float*)d_in[0];   // (B, T, IMG)
    const float* W0  = (const float*)d_in[1];   // (IMG, 4H)
    const float* W1  = (const float*)d_in[2];   // (H, 3H)
    const float* W2  = (const float*)d_in[3];   // (H, 3H)
    const float* vc0 = (const float*)d_in[4];
    const float* vc1 = (const float*)d_in[5];
    const float* vc2 = (const float*)d_in[6];
    const float* b0  = (const float*)d_in[7];
    const float* b1  = (const float*)d_in[8];
    const float* b2  = (const float*)d_in[9];
    const float* fcw = (const float*)d_in[10];  // (H, NCLASS)
    const float* fcb = (const float*)d_in[11];
    float* out = (float*)d_out;                 // (B, NCLASS)

    // --- choose batch-chunk size CB so the arena fits ws_size.
    // Arena floats per batch: U 12*4096 + hA 12*1024 + hB 12*1024 + hbar 1024
    //                       = 74752 floats = 299008 bytes.
    // CB must be a multiple of 32 so CB*12 is a multiple of 128 (GEMM BM).
    const size_t PER_B = 74752ull * sizeof(float);
    int CB = 32;
    if      (1024ull * PER_B <= ws_size) CB = 1024;
    else if ( 512ull * PER_B <= ws_size) CB = 512;
    else if ( 256ull * PER_B <= ws_size) CB = 256;
    else if ( 128ull * PER_B <= ws_size) CB = 128;
    else if (  64ull * PER_B <= ws_size) CB = 64;
    const int MC = CB * TSTEPS;                 // rows per chunk

    float* U    = (float*)d_ws;
    float* hA   = U  + (size_t)MC * 4096;
    float* hB   = hA + (size_t)MC * HIDN;
    float* hbar = hB + (size_t)MC * HIDN;

    const dim3 blk256(256);
    const dim3 rgrid((CB * HIDN) / 256);

    for (int cb = 0; cb < BATCH / CB; ++cb) {
        const float* xc   = x   + (size_t)cb * CB * TSTEPS * IMG;
        float*       outc = out + (size_t)cb * CB * NCLASS;

        // layer 0: xc(MC,512) @ W0(512,4096) -> U ; resid = U[:,3H:4H]
        gemm_f32<<<dim3(4096 / 128, MC / 128), blk256, 0, stream>>>(xc, W0, U, 4096, IMG);
        sru_recur<<<rgrid, blk256, 0, stream>>>(U, U + 3 * HIDN, vc0, b0, hA, nullptr, 4096, 4096);

        // layer 1: hA @ W1(1024,3072) -> U ; resid = hA
        gemm_f32<<<dim3(3072 / 128, MC / 128), blk256, 0, stream>>>(hA, W1, U, 3072, HIDN);
        sru_recur<<<rgrid, blk256, 0, stream>>>(U, hA, vc1, b1, hB, nullptr, 3072, HIDN);

        // layer 2: hB @ W2 -> U ; resid = hB ; emit hbar = mean_t h
        gemm_f32<<<dim3(3072 / 128, MC / 128), blk256, 0, stream>>>(hB, W2, U, 3072, HIDN);
        sru_recur<<<rgrid, blk256, 0, stream>>>(U, hB, vc2, b2, hA, hbar, 3072, HIDN);

        // final FC on time-averaged h
        final_fc<<<dim3(CB), dim3(64), 0, stream>>>(hbar, fcw, fcb, outc);
    }
}

// Round 3
// 1842.619 us; speedup vs baseline: 2.9919x; 2.9919x over previous
//
#include <hip/hip_runtime.h>
#include <hip/hip_bf16.h>
#include <math.h>

#define TSTEPS 12
#define BATCH  2048
#define IMG    512
#define HIDN   1024
#define NCLASS 51
#define SCALE_X 1.7320508075688772f      // sqrt(1 + 2*e^0) = sqrt(3)

typedef __attribute__((ext_vector_type(8))) short  s16x8;
typedef __attribute__((ext_vector_type(4))) float  f32x4;

// ---- bf16 helpers (raw-bits ushort, RNE rounding) --------------------------
__device__ __forceinline__ unsigned short f2bf(float f) {
    union { float f; unsigned u; } v; v.f = f;
    unsigned r = v.u + 0x7fffu + ((v.u >> 16) & 1u);   // round-to-nearest-even
    return (unsigned short)(r >> 16);
}
__device__ __forceinline__ float bf2f(unsigned short u) {
    union { unsigned u; float f; } v; v.u = ((unsigned)u) << 16;
    return v.f;
}

// ---------------------------------------------------------------------------
// Split-bf16 MFMA GEMM (3-term): C[M,N] fp32 = A[M,K] * B[K,N]
//   A given as hi/lo bf16 planes, row-major M x K.
//   B given as hi/lo bf16 planes of B^T, row-major N x K.
// BM=BN=128, BK=32, 256 threads (4 waves, 2x2), each wave 64x64 via 4x4
// mfma_f32_16x16x32_bf16. Staging: wave w async-copies plane w via
// global_load_lds width=16 (wave-uniform LDS base + lane*16).
// M % 128 == 0, N % 128 == 0, K % 32 == 0.
// ---------------------------------------------------------------------------
__global__ __launch_bounds__(256)
void gemm_split3(const unsigned short* __restrict__ Ahi,
                 const unsigned short* __restrict__ Alo,
                 const unsigned short* __restrict__ Bthi,
                 const unsigned short* __restrict__ Btlo,
                 float* __restrict__ C, int N, int K) {
    __shared__ unsigned short lds[4][128 * 32];   // 4 planes x 8 KB = 32 KB

    const int tid  = threadIdx.x;
    const int lane = tid & 63;
    const int w    = tid >> 6;                    // wave id 0..3
    const int bm   = blockIdx.y * 128;
    const int bn   = blockIdx.x * 128;

    // this wave's staging plane
    const unsigned short* splane = (w == 0) ? Ahi : (w == 1) ? Alo
                                 : (w == 2) ? Bthi : Btlo;
    const int srow0 = (w < 2) ? bm : bn;
    unsigned short* lbase = lds[w];               // wave-uniform LDS base
    const int lrow = lane >> 2;                   // 16 rows per instruction
    const int lcol = (lane & 3) * 8;              // shorts; 16 B per lane

    const int wy = (w >> 1) * 64;                 // wave tile origin in block
    const int wx = (w & 1) * 64;

    f32x4 zero = {0.f, 0.f, 0.f, 0.f};
    f32x4 acc[4][4];
    #pragma unroll
    for (int i = 0; i < 4; ++i)
        #pragma unroll
        for (int j = 0; j < 4; ++j) acc[i][j] = zero;

    const int kq = (lane >> 4) * 8;               // fragment k-offset (shorts)
    const int mr = lane & 15;                     // fragment row/col in tile

    for (int k0 = 0; k0 < K; k0 += 32) {
        const unsigned short* g = splane + (size_t)(srow0 + lrow) * K + k0 + lcol;
        #pragma unroll
        for (int j = 0; j < 8; ++j) {             // 8 x 1KB = full 8 KB plane
            __builtin_amdgcn_global_load_lds(
                (const __attribute__((address_space(1))) unsigned int*)(g + (size_t)j * 16 * K),
                (__attribute__((address_space(3))) unsigned int*)(lbase + j * 512),
                16, 0, 0);
        }
        __syncthreads();

        s16x8 ah[4], al[4], bh[4], bl[4];
        #pragma unroll
        for (int i = 0; i < 4; ++i) {
            ah[i] = *(const s16x8*)&lds[0][(wy + i * 16 + mr) * 32 + kq];
            al[i] = *(const s16x8*)&lds[1][(wy + i * 16 + mr) * 32 + kq];
            bh[i] = *(const s16x8*)&lds[2][(wx + i * 16 + mr) * 32 + kq];
            bl[i] = *(const s16x8*)&lds[3][(wx + i * 16 + mr) * 32 + kq];
        }
        #pragma unroll
        for (int i = 0; i < 4; ++i)
            #pragma unroll
            for (int j = 0; j < 4; ++j) {
                acc[i][j] = __builtin_amdgcn_mfma_f32_16x16x32_bf16(ah[i], bh[j], acc[i][j], 0, 0, 0);
                acc[i][j] = __builtin_amdgcn_mfma_f32_16x16x32_bf16(ah[i], bl[j], acc[i][j], 0, 0, 0);
                acc[i][j] = __builtin_amdgcn_mfma_f32_16x16x32_bf16(al[i], bh[j], acc[i][j], 0, 0, 0);
            }
        __syncthreads();
    }

    // C/D layout: col = lane&15, row = (lane>>4)*4 + r   [m89-verified]
    const int crow0 = bm + wy + ((lane >> 4) << 2);
    const int ccol0 = bn + wx + mr;
    #pragma unroll
    for (int i = 0; i < 4; ++i)
        #pragma unroll
        for (int j = 0; j < 4; ++j)
            #pragma unroll
            for (int r = 0; r < 4; ++r)
                C[(size_t)(crow0 + i * 16 + r) * N + ccol0 + j * 16] = acc[i][j][r];
}

// ---------------------------------------------------------------------------
// Weight transpose + hi/lo split:  W (K x N fp32) -> Wt_hi/lo (N x K bf16)
// ---------------------------------------------------------------------------
__global__ __launch_bounds__(256)
void wsplit_t(const float* __restrict__ W, unsigned short* __restrict__ hi,
              unsigned short* __restrict__ lo, int K, int N) {
    __shared__ float tile[32][33];
    const int bn = blockIdx.x * 32;
    const int bk = blockIdx.y * 32;
    const int tx = threadIdx.x & 31;
    const int ty = threadIdx.x >> 5;              // 0..7
    #pragma unroll
    for (int i = 0; i < 32; i += 8)
        tile[ty + i][tx] = W[(size_t)(bk + ty + i) * N + bn + tx];
    __syncthreads();
    #pragma unroll
    for (int i = 0; i < 32; i += 8) {
        float v = tile[tx][ty + i];               // = W[bk+tx][bn+ty+i]
        unsigned short h = f2bf(v);
        size_t o = (size_t)(bn + ty + i) * K + bk + tx;
        hi[o] = h;
        lo[o] = f2bf(v - bf2f(h));
    }
}

// elementwise hi/lo split (for x chunks), layout preserved
__global__ __launch_bounds__(256)
void esplit(const float* __restrict__ src, unsigned short* __restrict__ hi,
            unsigned short* __restrict__ lo, int n) {
    int i = blockIdx.x * 256 + threadIdx.x;
    if (i < n) {
        float v = src[i];
        unsigned short h = f2bf(v);
        hi[i] = h;
        lo[i] = f2bf(v - bf2f(h));
    }
}

// ---------------------------------------------------------------------------
// SRU recurrence over T=12. One thread per (b_local, h).
// U fp32, rows (b,t), row stride ustride; u0/u1/u2 at cols 0/H/2H.
// resid: fp32 ptr (layer0, stride rstride) OR hi/lo bf16 planes (stride H).
// Output h written as hi/lo bf16 planes (or skipped); hbar optional.
// ---------------------------------------------------------------------------
__global__ __launch_bounds__(256)
void sru_recur(const float* __restrict__ U, int ustride,
               const float* __restrict__ residf, int rstride,
               const unsigned short* __restrict__ rhi,
               const unsigned short* __restrict__ rlo,
               const float* __restrict__ vc, const float* __restrict__ bias,
               unsigned short* __restrict__ hhi, unsigned short* __restrict__ hlo,
               float* __restrict__ hbar) {
    const int idx = blockIdx.x * 256 + threadIdx.x;
    const int b = idx >> 10;
    const int h = idx & (HIDN - 1);

    const float vf = vc[h],  vr = vc[HIDN + h];
    const float bf_ = bias[h], br = bias[HIDN + h];

    float c = 0.f, sum = 0.f;
    size_t urow = (size_t)b * TSTEPS * ustride + h;
    size_t rrow = (size_t)b * TSTEPS * rstride + h;
    size_t orow = (size_t)b * TSTEPS * HIDN   + h;

    #pragma unroll
    for (int t = 0; t < TSTEPS; ++t) {
        const float u0 = U[urow];
        const float u1 = U[urow + HIDN];
        const float u2 = U[urow + 2 * HIDN];
        const float xt = residf ? residf[rrow]
                                : (bf2f(rhi[rrow]) + bf2f(rlo[rrow]));

        const float f = 1.f / (1.f + __expf(-(u1 + vf * c + bf_)));
        c = f * c + (1.f - f) * u0;
        const float r = 1.f / (1.f + __expf(-(u2 + vr * c + br)));
        const float hv = r * tanhf(c) + (1.f - r) * xt * SCALE_X;

        if (hhi) {
            unsigned short hb = f2bf(hv);
            hhi[orow] = hb;
            hlo[orow] = f2bf(hv - bf2f(hb));
        }
        sum += hv;
        urow += ustride; rrow += rstride; orow += HIDN;
    }
    if (hbar) hbar[(size_t)b * HIDN + h] = sum * (1.f / TSTEPS);
}

// ---------------------------------------------------------------------------
// Final FC on time-averaged h: out[b,c] = hbar[b,:] . fc_w[:,c] + fc_b[c]
// ---------------------------------------------------------------------------
__global__ __launch_bounds__(64)
void final_fc(const float* __restrict__ hbar, const float* __restrict__ fcw,
              const float* __restrict__ fcb, float* __restrict__ out) {
    __shared__ float hrow[HIDN];
    const int b = blockIdx.x;
    for (int i = threadIdx.x; i < HIDN; i += 64)
        hrow[i] = hbar[(size_t)b * HIDN + i];
    __syncthreads();

    const int c = threadIdx.x;
    if (c < NCLASS) {
        float acc = fcb[c];
        #pragma unroll 8
        for (int k = 0; k < HIDN; ++k)
            acc = fmaf(hrow[k], fcw[(size_t)k * NCLASS + c], acc);
        out[(size_t)b * NCLASS + c] = acc;
    }
}

// ---------------------------------------------------------------------------
extern "C" void kernel_launch(void* const* d_in, const int* in_sizes, int n_in,
                              void* d_out, int out_size, void* d_ws, size_t ws_size,
                              hipStream_t stream) {
    const float* x   = (const float*)d_in[0];   // (B, T, IMG)
    const float* W0  = (const float*)d_in[1];   // (IMG, 4H)
    const float* W1  = (const float*)d_in[2];   // (H, 3H)
    const float* W2  = (const float*)d_in[3];   // (H, 3H)
    const float* vc0 = (const float*)d_in[4];
    const float* vc1 = (const float*)d_in[5];
    const float* vc2 = (const float*)d_in[6];
    const float* b0  = (const float*)d_in[7];
    const float* b1  = (const float*)d_in[8];
    const float* b2  = (const float*)d_in[9];
    const float* fcw = (const float*)d_in[10];  // (H, NCLASS)
    const float* fcb = (const float*)d_in[11];
    float* out = (float*)d_out;                 // (B, NCLASS)

    // ---- workspace carve-up -------------------------------------------------
    // fixed: transposed+split weight planes (32 MB)
    char* ws = (char*)d_ws;
    size_t off = 0;
    auto carve = [&](size_t bytes) { char* p = ws + off; off = (off + bytes + 255) & ~255ull; return p; };

    unsigned short* W0thi = (unsigned short*)carve((size_t)4096 * 512 * 2);
    unsigned short* W0tlo = (unsigned short*)carve((size_t)4096 * 512 * 2);
    unsigned short* W1thi = (unsigned short*)carve((size_t)3072 * 1024 * 2);
    unsigned short* W1tlo = (unsigned short*)carve((size_t)3072 * 1024 * 2);
    unsigned short* W2thi = (unsigned short*)carve((size_t)3072 * 1024 * 2);
    unsigned short* W2tlo = (unsigned short*)carve((size_t)3072 * 1024 * 2);
    const size_t W_BYTES = off;

    // per-batch arena bytes: U + x planes + hA planes + hB planes + hbar
    const size_t PER_B = 12ull * 4096 * 4 + 2ull * 12 * 512 * 2
                       + 4ull * 12 * 1024 * 2 + 1024ull * 4 + 2048; // + align slack
    int CB = 32;
    if      (W_BYTES + 1024ull * PER_B <= ws_size) CB = 1024;
    else if (W_BYTES +  512ull * PER_B <= ws_size) CB = 512;
    else if (W_BYTES +  256ull * PER_B <= ws_size) CB = 256;
    else if (W_BYTES +  128ull * PER_B <= ws_size) CB = 128;
    else if (W_BYTES +   64ull * PER_B <= ws_size) CB = 64;
    const int MC = CB * TSTEPS;                 // rows per chunk (mult of 128: CB%32==0 -> MC%384; need %128 -> CB mult of 32 gives MC=384k, 384%128=0 only if k%... )
    // NOTE: MC must be divisible by 128. CB in {32,64,128,256,512,1024} gives
    // MC in {384,768,1536,3072,6144,12288} — all divisible by 128 except 384
    // (384 = 3*128 ✓) — all fine.

    float*          U     = (float*)carve((size_t)MC * 4096 * 4);
    unsigned short* xhi   = (unsigned short*)carve((size_t)MC * 512 * 2);
    unsigned short* xlo   = (unsigned short*)carve((size_t)MC * 512 * 2);
    unsigned short* hAhi  = (unsigned short*)carve((size_t)MC * 1024 * 2);
    unsigned short* hAlo  = (unsigned short*)carve((size_t)MC * 1024 * 2);
    unsigned short* hBhi  = (unsigned short*)carve((size_t)MC * 1024 * 2);
    unsigned short* hBlo  = (unsigned short*)carve((size_t)MC * 1024 * 2);
    float*          hbar  = (float*)carve((size_t)CB * 1024 * 4);

    const dim3 blk256(256);
    const dim3 rgrid((CB * HIDN) / 256);

    // ---- per-call weight prep ----------------------------------------------
    wsplit_t<<<dim3(4096 / 32, 512 / 32),  blk256, 0, stream>>>(W0, W0thi, W0tlo, 512, 4096);
    wsplit_t<<<dim3(3072 / 32, 1024 / 32), blk256, 0, stream>>>(W1, W1thi, W1tlo, 1024, 3072);
    wsplit_t<<<dim3(3072 / 32, 1024 / 32), blk256, 0, stream>>>(W2, W2thi, W2tlo, 1024, 3072);

    for (int cb = 0; cb < BATCH / CB; ++cb) {
        const float* xc   = x   + (size_t)cb * CB * TSTEPS * IMG;
        float*       outc = out + (size_t)cb * CB * NCLASS;

        // layer 0: split x, then U = x @ W0 (N=4096, K=512); resid = U[:,3H:]
        esplit<<<dim3((MC * 512) / 256), blk256, 0, stream>>>(xc, xhi, xlo, MC * 512);
        gemm_split3<<<dim3(4096 / 128, MC / 128), blk256, 0, stream>>>(
            xhi, xlo, W0thi, W0tlo, U, 4096, 512);
        sru_recur<<<rgrid, blk256, 0, stream>>>(U, 4096, U + 3 * HIDN, 4096,
            nullptr, nullptr, vc0, b0, hAhi, hAlo, nullptr);

        // layer 1: U = hA @ W1 (N=3072, K=1024); resid = hA planes
        gemm_split3<<<dim3(3072 / 128, MC / 128), blk256, 0, stream>>>(
            hAhi, hAlo, W1thi, W1tlo, U, 3072, 1024);
        sru_recur<<<rgrid, blk256, 0, stream>>>(U, 3072, nullptr, HIDN,
            hAhi, hAlo, vc1, b1, hBhi, hBlo, nullptr);

        // layer 2: U = hB @ W2; resid = hB planes; emit hbar only
        gemm_split3<<<dim3(3072 / 128, MC / 128), blk256, 0, stream>>>(
            hBhi, hBlo, W2thi, W2tlo, U, 3072, 1024);
        sru_recur<<<rgrid, blk256, 0, stream>>>(U, 3072, nullptr, HIDN,
            hBhi, hBlo, vc2, b2, nullptr, nullptr, hbar);

        // final FC on time-averaged h
        final_fc<<<dim3(CB), dim3(64), 0, stream>>>(hbar, fcw, fcb, outc);
    }
}

// Round 4
// 1229.709 us; speedup vs baseline: 4.4831x; 1.4984x over previous
//
#include <hip/hip_runtime.h>
#include <math.h>

#define TSTEPS 12
#define BATCH  2048
#define IMG    512
#define HIDN   1024
#define NCLASS 51
#define SCALE_X 1.7320508075688772f      // sqrt(1 + 2*e^0) = sqrt(3)

typedef __attribute__((ext_vector_type(8))) _Float16 f16x8;
typedef __attribute__((ext_vector_type(4))) float    f32x4;

// ---------------------------------------------------------------------------
// fp16 MFMA GEMM: C[M,N] fp32 = A[M,K] * B[K,N]
//   A fp16 row-major M x K; B given as fp16 B^T, row-major N x K.
// BM=BN=128, BK=32, 256 threads (4 waves, 2x2), each wave 64x64 via 4x4
// mfma_f32_16x16x32_f16. Staging: waves 0,1 stage A rows [0,64)/[64,128),
// waves 2,3 stage B^T rows, via global_load_lds width=16.
// M % 128 == 0, N % 128 == 0, K % 32 == 0.
// ---------------------------------------------------------------------------
__global__ __launch_bounds__(256)
void gemm_f16(const _Float16* __restrict__ A, const _Float16* __restrict__ Bt,
              float* __restrict__ C, int N, int K) {
    __shared__ _Float16 ldsA[128 * 32];           // 8 KB
    __shared__ _Float16 ldsB[128 * 32];           // 8 KB

    const int tid  = threadIdx.x;
    const int lane = tid & 63;
    const int w    = tid >> 6;                    // wave id 0..3
    const int bm   = blockIdx.y * 128;
    const int bn   = blockIdx.x * 128;

    // staging assignment: w<2 -> A, else B; (w&1) selects 64-row half
    const _Float16* splane = (w < 2) ? A : Bt;
    const int srow0 = ((w < 2) ? bm : bn) + (w & 1) * 64;
    _Float16* lbase = ((w < 2) ? ldsA : ldsB) + (w & 1) * (64 * 32);
    const int lrow = lane >> 2;                   // 16 rows per instruction
    const int lcol = (lane & 3) * 8;              // halfs; 16 B per lane

    const int wy = (w >> 1) * 64;                 // wave tile origin in block
    const int wx = (w & 1) * 64;

    f32x4 acc[4][4];
    #pragma unroll
    for (int i = 0; i < 4; ++i)
        #pragma unroll
        for (int j = 0; j < 4; ++j) acc[i][j] = (f32x4){0.f, 0.f, 0.f, 0.f};

    const int kq = (lane >> 4) * 8;               // fragment k-offset (halfs)
    const int mr = lane & 15;                     // fragment row/col in tile

    for (int k0 = 0; k0 < K; k0 += 32) {
        const _Float16* g = splane + (size_t)(srow0 + lrow) * K + k0 + lcol;
        #pragma unroll
        for (int j = 0; j < 4; ++j) {             // 4 x 1KB = this wave's 4 KB
            __builtin_amdgcn_global_load_lds(
                (const __attribute__((address_space(1))) unsigned int*)(g + (size_t)j * 16 * K),
                (__attribute__((address_space(3))) unsigned int*)(lbase + j * 512),
                16, 0, 0);
        }
        __syncthreads();

        f16x8 a[4], b[4];
        #pragma unroll
        for (int i = 0; i < 4; ++i) {
            a[i] = *(const f16x8*)&ldsA[(wy + i * 16 + mr) * 32 + kq];
            b[i] = *(const f16x8*)&ldsB[(wx + i * 16 + mr) * 32 + kq];
        }
        #pragma unroll
        for (int i = 0; i < 4; ++i)
            #pragma unroll
            for (int j = 0; j < 4; ++j)
                acc[i][j] = __builtin_amdgcn_mfma_f32_16x16x32_f16(a[i], b[j], acc[i][j], 0, 0, 0);
        __syncthreads();
    }

    // C/D layout: col = lane&15, row = (lane>>4)*4 + r   [m89-verified]
    const int crow0 = bm + wy + ((lane >> 4) << 2);
    const int ccol0 = bn + wx + mr;
    #pragma unroll
    for (int i = 0; i < 4; ++i)
        #pragma unroll
        for (int j = 0; j < 4; ++j)
            #pragma unroll
            for (int r = 0; r < 4; ++r)
                C[(size_t)(crow0 + i * 16 + r) * N + ccol0 + j * 16] = acc[i][j][r];
}

// ---------------------------------------------------------------------------
// Weight transpose + fp16 convert:  W (K x N fp32) -> Wt (N x K fp16)
// ---------------------------------------------------------------------------
__global__ __launch_bounds__(256)
void wsplit_t(const float* __restrict__ W, _Float16* __restrict__ Wt,
              int K, int N) {
    __shared__ float tile[32][33];
    const int bn = blockIdx.x * 32;
    const int bk = blockIdx.y * 32;
    const int tx = threadIdx.x & 31;
    const int ty = threadIdx.x >> 5;              // 0..7
    #pragma unroll
    for (int i = 0; i < 32; i += 8)
        tile[ty + i][tx] = W[(size_t)(bk + ty + i) * N + bn + tx];
    __syncthreads();
    #pragma unroll
    for (int i = 0; i < 32; i += 8)
        Wt[(size_t)(bn + ty + i) * K + bk + tx] = (_Float16)tile[tx][ty + i];
}

// elementwise fp32 -> fp16 convert (for x chunks)
__global__ __launch_bounds__(256)
void esplit(const float* __restrict__ src, _Float16* __restrict__ dst, int n) {
    int i = blockIdx.x * 256 + threadIdx.x;
    if (i < n) dst[i] = (_Float16)src[i];
}

// ---------------------------------------------------------------------------
// SRU recurrence over T=12. One thread per (b_local, h).
// U fp32, rows (b,t), row stride ustride; u0/u1/u2 at cols 0/H/2H.
// resid: fp32 ptr (layer0, stride rstride) OR fp16 plane (stride H).
// Output h written as fp16 (or skipped); hbar (mean_t h, fp32) optional.
// ---------------------------------------------------------------------------
__global__ __launch_bounds__(256)
void sru_recur(const float* __restrict__ U, int ustride,
               const float* __restrict__ residf, int rstride,
               const _Float16* __restrict__ rh,
               const float* __restrict__ vc, const float* __restrict__ bias,
               _Float16* __restrict__ hout, float* __restrict__ hbar) {
    const int idx = blockIdx.x * 256 + threadIdx.x;
    const int b = idx >> 10;
    const int h = idx & (HIDN - 1);

    const float vf = vc[h],  vr = vc[HIDN + h];
    const float bf_ = bias[h], br = bias[HIDN + h];

    float c = 0.f, sum = 0.f;
    size_t urow = (size_t)b * TSTEPS * ustride + h;
    size_t rrow = (size_t)b * TSTEPS * rstride + h;
    size_t orow = (size_t)b * TSTEPS * HIDN   + h;

    #pragma unroll
    for (int t = 0; t < TSTEPS; ++t) {
        const float u0 = U[urow];
        const float u1 = U[urow + HIDN];
        const float u2 = U[urow + 2 * HIDN];
        const float xt = residf ? residf[rrow] : (float)rh[rrow];

        const float f = 1.f / (1.f + __expf(-(u1 + vf * c + bf_)));
        c = f * c + (1.f - f) * u0;
        const float r = 1.f / (1.f + __expf(-(u2 + vr * c + br)));
        const float hv = r * tanhf(c) + (1.f - r) * xt * SCALE_X;

        if (hout) hout[orow] = (_Float16)hv;
        sum += hv;
        urow += ustride; rrow += rstride; orow += HIDN;
    }
    if (hbar) hbar[(size_t)b * HIDN + h] = sum * (1.f / TSTEPS);
}

// ---------------------------------------------------------------------------
// Final FC on time-averaged h: out[b,c] = hbar[b,:] . fc_w[:,c] + fc_b[c]
// ---------------------------------------------------------------------------
__global__ __launch_bounds__(64)
void final_fc(const float* __restrict__ hbar, const float* __restrict__ fcw,
              const float* __restrict__ fcb, float* __restrict__ out) {
    __shared__ float hrow[HIDN];
    const int b = blockIdx.x;
    for (int i = threadIdx.x; i < HIDN; i += 64)
        hrow[i] = hbar[(size_t)b * HIDN + i];
    __syncthreads();

    const int c = threadIdx.x;
    if (c < NCLASS) {
        float acc = fcb[c];
        #pragma unroll 8
        for (int k = 0; k < HIDN; ++k)
            acc = fmaf(hrow[k], fcw[(size_t)k * NCLASS + c], acc);
        out[(size_t)b * NCLASS + c] = acc;
    }
}

// ---------------------------------------------------------------------------
extern "C" void kernel_launch(void* const* d_in, const int* in_sizes, int n_in,
                              void* d_out, int out_size, void* d_ws, size_t ws_size,
                              hipStream_t stream) {
    const float* x   = (const float*)d_in[0];   // (B, T, IMG)
    const float* W0  = (const float*)d_in[1];   // (IMG, 4H)
    const float* W1  = (const float*)d_in[2];   // (H, 3H)
    const float* W2  = (const float*)d_in[3];   // (H, 3H)
    const float* vc0 = (const float*)d_in[4];
    const float* vc1 = (const float*)d_in[5];
    const float* vc2 = (const float*)d_in[6];
    const float* b0  = (const float*)d_in[7];
    const float* b1  = (const float*)d_in[8];
    const float* b2  = (const float*)d_in[9];
    const float* fcw = (const float*)d_in[10];  // (H, NCLASS)
    const float* fcb = (const float*)d_in[11];
    float* out = (float*)d_out;                 // (B, NCLASS)

    // ---- workspace carve-up -------------------------------------------------
    char* ws = (char*)d_ws;
    size_t off = 0;
    auto carve = [&](size_t bytes) { char* p = ws + off; off = (off + bytes + 255) & ~255ull; return p; };

    _Float16* W0t = (_Float16*)carve((size_t)4096 * 512 * 2);   // 4 MB
    _Float16* W1t = (_Float16*)carve((size_t)3072 * 1024 * 2);  // 6 MB
    _Float16* W2t = (_Float16*)carve((size_t)3072 * 1024 * 2);  // 6 MB
    const size_t W_BYTES = off;

    // per-batch arena: U(12*4096*4) + x16(12*512*2) + hA16 + hB16 + hbar
    const size_t PER_B = 12ull * 4096 * 4 + 12ull * 512 * 2
                       + 2ull * 12 * 1024 * 2 + 1024ull * 4 + 2048;
    int CB = 32;
    if      (W_BYTES + 2048ull * PER_B <= ws_size) CB = 2048;
    else if (W_BYTES + 1024ull * PER_B <= ws_size) CB = 1024;
    else if (W_BYTES +  512ull * PER_B <= ws_size) CB = 512;
    else if (W_BYTES +  256ull * PER_B <= ws_size) CB = 256;
    else if (W_BYTES +  128ull * PER_B <= ws_size) CB = 128;
    else if (W_BYTES +   64ull * PER_B <= ws_size) CB = 64;
    const int MC = CB * TSTEPS;   // rows per chunk; CB mult of 32 -> MC mult of 384 (div by 128 OK)

    float*    U    = (float*)carve((size_t)MC * 4096 * 4);
    _Float16* x16  = (_Float16*)carve((size_t)MC * 512 * 2);
    _Float16* hA16 = (_Float16*)carve((size_t)MC * 1024 * 2);
    _Float16* hB16 = (_Float16*)carve((size_t)MC * 1024 * 2);
    float*    hbar = (float*)carve((size_t)CB * 1024 * 4);

    const dim3 blk256(256);
    const dim3 rgrid((CB * HIDN) / 256);

    // ---- per-call weight prep ----------------------------------------------
    wsplit_t<<<dim3(4096 / 32, 512 / 32),  blk256, 0, stream>>>(W0, W0t, 512, 4096);
    wsplit_t<<<dim3(3072 / 32, 1024 / 32), blk256, 0, stream>>>(W1, W1t, 1024, 3072);
    wsplit_t<<<dim3(3072 / 32, 1024 / 32), blk256, 0, stream>>>(W2, W2t, 1024, 3072);

    for (int cb = 0; cb < BATCH / CB; ++cb) {
        const float* xc   = x   + (size_t)cb * CB * TSTEPS * IMG;
        float*       outc = out + (size_t)cb * CB * NCLASS;

        // layer 0: x->fp16, U = x @ W0 (N=4096, K=512); resid = U[:,3H:]
        esplit<<<dim3((MC * 512) / 256), blk256, 0, stream>>>(xc, x16, MC * 512);
        gemm_f16<<<dim3(4096 / 128, MC / 128), blk256, 0, stream>>>(x16, W0t, U, 4096, 512);
        sru_recur<<<rgrid, blk256, 0, stream>>>(U, 4096, U + 3 * HIDN, 4096,
            nullptr, vc0, b0, hA16, nullptr);

        // layer 1: U = hA @ W1 (N=3072, K=1024); resid = hA (fp16)
        gemm_f16<<<dim3(3072 / 128, MC / 128), blk256, 0, stream>>>(hA16, W1t, U, 3072, 1024);
        sru_recur<<<rgrid, blk256, 0, stream>>>(U, 3072, nullptr, HIDN,
            hA16, vc1, b1, hB16, nullptr);

        // layer 2: U = hB @ W2; resid = hB (fp16); emit hbar only
        gemm_f16<<<dim3(3072 / 128, MC / 128), blk256, 0, stream>>>(hB16, W2t, U, 3072, 1024);
        sru_recur<<<rgrid, blk256, 0, stream>>>(U, 3072, nullptr, HIDN,
            hB16, vc2, b2, nullptr, hbar);

        // final FC on time-averaged h
        final_fc<<<dim3(CB), dim3(64), 0, stream>>>(hbar, fcw, fcb, outc);
    }
}

// Round 5
// 926.379 us; speedup vs baseline: 5.9510x; 1.3274x over previous
//
#include <hip/hip_runtime.h>
#include <math.h>

#define TSTEPS 12
#define BATCH  2048
#define IMG    512
#define HIDN   1024
#define NCLASS 51
#define SCALE_X 1.7320508075688772f      // sqrt(1 + 2*e^0) = sqrt(3)

typedef __attribute__((ext_vector_type(8))) _Float16 f16x8;
typedef __attribute__((ext_vector_type(2))) _Float16 f16x2;
typedef __attribute__((ext_vector_type(4))) float    f32x4;

// ---------------------------------------------------------------------------
// fp16 MFMA GEMM, double-buffered staging: C[M,N] fp16 = A[M,K] * B[K,N]
//   A fp16 row-major M x K; B given as fp16 B^T, row-major N x K.
// BM=BN=128, BK=32, 256 threads (4 waves), each wave 64x64 via 4x4
// mfma_f32_16x16x32_f16. Staging: wave w async-copies its operand-half via
// global_load_lds width=16 into buf[cur^1] while computing on buf[cur];
// the __syncthreads vmcnt(0) drain thus waits on loads that are one full
// compute phase old (latency hidden).
// M % 128 == 0, N % 128 == 0, K % 32 == 0, K >= 64.
// ---------------------------------------------------------------------------
__global__ __launch_bounds__(256)
void gemm_f16(const _Float16* __restrict__ A, const _Float16* __restrict__ Bt,
              _Float16* __restrict__ C, int N, int K) {
    __shared__ _Float16 lds[2][2 * 128 * 32];     // [buf][A(8KB) | B(8KB)] = 32 KB

    const int tid  = threadIdx.x;
    const int lane = tid & 63;
    const int w    = tid >> 6;                    // wave id 0..3
    const int bm   = blockIdx.y * 128;
    const int bn   = blockIdx.x * 128;

    // staging assignment: w<2 -> A, else B; (w&1) selects 64-row half
    const _Float16* splane = (w < 2) ? A : Bt;
    const int srow0 = ((w < 2) ? bm : bn) + (w & 1) * 64;
    const int lhalf = (w >> 1) * (128 * 32) + (w & 1) * (64 * 32); // wave-uniform
    const int lrow = lane >> 2;                   // 16 rows per instruction
    const int lcol = (lane & 3) * 8;              // halfs; 16 B per lane

    const int wy = (w >> 1) * 64;                 // wave tile origin in block
    const int wx = (w & 1) * 64;

    f32x4 acc[4][4];
    #pragma unroll
    for (int i = 0; i < 4; ++i)
        #pragma unroll
        for (int j = 0; j < 4; ++j) acc[i][j] = (f32x4){0.f, 0.f, 0.f, 0.f};

    const int kq = (lane >> 4) * 8;               // fragment k-offset (halfs)
    const int mr = lane & 15;                     // fragment row/col in tile

    const _Float16* gbase = splane + (size_t)(srow0 + lrow) * K + lcol;

    // stage this wave's 4 KB half of operand plane for k-chunk k0 into buf
    auto stage = [&](int buf, int k0) {
        const _Float16* g = gbase + k0;
        _Float16* l = &lds[buf][lhalf];           // wave-uniform LDS base
        #pragma unroll
        for (int j = 0; j < 4; ++j)
            __builtin_amdgcn_global_load_lds(
                (const __attribute__((address_space(1))) unsigned int*)(g + (size_t)j * 16 * K),
                (__attribute__((address_space(3))) unsigned int*)(l + j * 512),
                16, 0, 0);
    };

    stage(0, 0);                                  // prologue prefetch

    int cur = 0;
    for (int k0 = 0; k0 < K; k0 += 32) {
        __syncthreads();   // drains: cur-buf loads (issued 1 compute phase ago)
                           // + all waves done reading the buffer we refill next
        if (k0 + 32 < K) stage(cur ^ 1, k0 + 32);

        const _Float16* la = &lds[cur][0];
        const _Float16* lb = &lds[cur][128 * 32];
        f16x8 a[4], b[4];
        #pragma unroll
        for (int i = 0; i < 4; ++i) {
            a[i] = *(const f16x8*)&la[(wy + i * 16 + mr) * 32 + kq];
            b[i] = *(const f16x8*)&lb[(wx + i * 16 + mr) * 32 + kq];
        }
        #pragma unroll
        for (int i = 0; i < 4; ++i)
            #pragma unroll
            for (int j = 0; j < 4; ++j)
                acc[i][j] = __builtin_amdgcn_mfma_f32_16x16x32_f16(a[i], b[j], acc[i][j], 0, 0, 0);
        cur ^= 1;
    }

    // C/D layout: col = lane&15, row = (lane>>4)*4 + r   [m89-verified]
    const int crow0 = bm + wy + ((lane >> 4) << 2);
    const int ccol0 = bn + wx + mr;
    #pragma unroll
    for (int i = 0; i < 4; ++i)
        #pragma unroll
        for (int j = 0; j < 4; ++j)
            #pragma unroll
            for (int r = 0; r < 4; ++r)
                C[(size_t)(crow0 + i * 16 + r) * N + ccol0 + j * 16] =
                    (_Float16)acc[i][j][r];
}

// ---------------------------------------------------------------------------
// Weight transpose + fp16 convert:  W (K x N fp32) -> Wt (N x K fp16)
// ---------------------------------------------------------------------------
__global__ __launch_bounds__(256)
void wsplit_t(const float* __restrict__ W, _Float16* __restrict__ Wt,
              int K, int N) {
    __shared__ float tile[32][33];
    const int bn = blockIdx.x * 32;
    const int bk = blockIdx.y * 32;
    const int tx = threadIdx.x & 31;
    const int ty = threadIdx.x >> 5;              // 0..7
    #pragma unroll
    for (int i = 0; i < 32; i += 8)
        tile[ty + i][tx] = W[(size_t)(bk + ty + i) * N + bn + tx];
    __syncthreads();
    #pragma unroll
    for (int i = 0; i < 32; i += 8)
        Wt[(size_t)(bn + ty + i) * K + bk + tx] = (_Float16)tile[tx][ty + i];
}

// elementwise fp32 -> fp16 convert (for x chunks)
__global__ __launch_bounds__(256)
void esplit(const float* __restrict__ src, _Float16* __restrict__ dst, int n) {
    int i = blockIdx.x * 256 + threadIdx.x;
    if (i < n) dst[i] = (_Float16)src[i];
}

// ---------------------------------------------------------------------------
// SRU recurrence over T=12. One thread per (b_local, 2 channels).
// U fp16, rows (b,t), row stride ustride; u0/u1/u2 at cols 0/H/2H.
// resid: fp16 plane, row stride rstride (layer0: U+3H, stride 4H).
// Output h fp16 (optional); hbar fp32 mean_t h (optional).
// ---------------------------------------------------------------------------
__global__ __launch_bounds__(256)
void sru_recur(const _Float16* __restrict__ U, int ustride,
               const _Float16* __restrict__ resid, int rstride,
               const float* __restrict__ vc, const float* __restrict__ bias,
               _Float16* __restrict__ hout, float* __restrict__ hbar) {
    const int idx = blockIdx.x * 256 + threadIdx.x;   // [0, CB*512)
    const int b = idx >> 9;
    const int h = (idx & 511) << 1;                   // even channel pair

    const float2 vf = *(const float2*)&vc[h];
    const float2 vr = *(const float2*)&vc[HIDN + h];
    const float2 bf_ = *(const float2*)&bias[h];
    const float2 br = *(const float2*)&bias[HIDN + h];

    float c0 = 0.f, c1 = 0.f, s0 = 0.f, s1 = 0.f;
    size_t urow = (size_t)b * TSTEPS * ustride + h;
    size_t rrow = (size_t)b * TSTEPS * rstride + h;
    size_t orow = (size_t)b * TSTEPS * HIDN   + h;

    #pragma unroll
    for (int t = 0; t < TSTEPS; ++t) {
        const f16x2 u0 = *(const f16x2*)&U[urow];
        const f16x2 u1 = *(const f16x2*)&U[urow + HIDN];
        const f16x2 u2 = *(const f16x2*)&U[urow + 2 * HIDN];
        const f16x2 xt = *(const f16x2*)&resid[rrow];

        {   // channel 0
            const float f = 1.f / (1.f + __expf(-((float)u1[0] + vf.x * c0 + bf_.x)));
            c0 = f * c0 + (1.f - f) * (float)u0[0];
            const float r = 1.f / (1.f + __expf(-((float)u2[0] + vr.x * c0 + br.x)));
            const float hv = r * tanhf(c0) + (1.f - r) * (float)xt[0] * SCALE_X;
            if (hout) hout[orow] = (_Float16)hv;
            s0 += hv;
        }
        {   // channel 1
            const float f = 1.f / (1.f + __expf(-((float)u1[1] + vf.y * c1 + bf_.y)));
            c1 = f * c1 + (1.f - f) * (float)u0[1];
            const float r = 1.f / (1.f + __expf(-((float)u2[1] + vr.y * c1 + br.y)));
            const float hv = r * tanhf(c1) + (1.f - r) * (float)xt[1] * SCALE_X;
            if (hout) hout[orow + 1] = (_Float16)hv;
            s1 += hv;
        }
        urow += ustride; rrow += rstride; orow += HIDN;
    }
    if (hbar) {
        float2 hb = make_float2(s0 * (1.f / TSTEPS), s1 * (1.f / TSTEPS));
        *(float2*)&hbar[(size_t)b * HIDN + h] = hb;
    }
}

// ---------------------------------------------------------------------------
// Final FC on time-averaged h: out[b,c] = hbar[b,:] . fc_w[:,c] + fc_b[c]
// ---------------------------------------------------------------------------
__global__ __launch_bounds__(64)
void final_fc(const float* __restrict__ hbar, const float* __restrict__ fcw,
              const float* __restrict__ fcb, float* __restrict__ out) {
    __shared__ float hrow[HIDN];
    const int b = blockIdx.x;
    for (int i = threadIdx.x; i < HIDN; i += 64)
        hrow[i] = hbar[(size_t)b * HIDN + i];
    __syncthreads();

    const int c = threadIdx.x;
    if (c < NCLASS) {
        float acc = fcb[c];
        #pragma unroll 8
        for (int k = 0; k < HIDN; ++k)
            acc = fmaf(hrow[k], fcw[(size_t)k * NCLASS + c], acc);
        out[(size_t)b * NCLASS + c] = acc;
    }
}

// ---------------------------------------------------------------------------
extern "C" void kernel_launch(void* const* d_in, const int* in_sizes, int n_in,
                              void* d_out, int out_size, void* d_ws, size_t ws_size,
                              hipStream_t stream) {
    const float* x   = (const float*)d_in[0];   // (B, T, IMG)
    const float* W0  = (const float*)d_in[1];   // (IMG, 4H)
    const float* W1  = (const float*)d_in[2];   // (H, 3H)
    const float* W2  = (const float*)d_in[3];   // (H, 3H)
    const float* vc0 = (const float*)d_in[4];
    const float* vc1 = (const float*)d_in[5];
    const float* vc2 = (const float*)d_in[6];
    const float* b0  = (const float*)d_in[7];
    const float* b1  = (const float*)d_in[8];
    const float* b2  = (const float*)d_in[9];
    const float* fcw = (const float*)d_in[10];  // (H, NCLASS)
    const float* fcb = (const float*)d_in[11];
    float* out = (float*)d_out;                 // (B, NCLASS)

    // ---- workspace carve-up -------------------------------------------------
    char* ws = (char*)d_ws;
    size_t off = 0;
    auto carve = [&](size_t bytes) { char* p = ws + off; off = (off + bytes + 255) & ~255ull; return p; };

    _Float16* W0t = (_Float16*)carve((size_t)4096 * 512 * 2);   // 4 MB
    _Float16* W1t = (_Float16*)carve((size_t)3072 * 1024 * 2);  // 6 MB
    _Float16* W2t = (_Float16*)carve((size_t)3072 * 1024 * 2);  // 6 MB
    const size_t W_BYTES = off;

    // per-batch arena: U16(12*4096*2) + x16(12*512*2) + hA16 + hB16 + hbar
    const size_t PER_B = 12ull * 4096 * 2 + 12ull * 512 * 2
                       + 2ull * 12 * 1024 * 2 + 1024ull * 4 + 2048;
    int CB = 32;
    if      (W_BYTES + 2048ull * PER_B <= ws_size) CB = 2048;
    else if (W_BYTES + 1024ull * PER_B <= ws_size) CB = 1024;
    else if (W_BYTES +  512ull * PER_B <= ws_size) CB = 512;
    else if (W_BYTES +  256ull * PER_B <= ws_size) CB = 256;
    else if (W_BYTES +  128ull * PER_B <= ws_size) CB = 128;
    else if (W_BYTES +   64ull * PER_B <= ws_size) CB = 64;
    const int MC = CB * TSTEPS;   // rows per chunk; multiple of 384 -> 128 | MC

    _Float16* U    = (_Float16*)carve((size_t)MC * 4096 * 2);
    _Float16* x16  = (_Float16*)carve((size_t)MC * 512 * 2);
    _Float16* hA16 = (_Float16*)carve((size_t)MC * 1024 * 2);
    _Float16* hB16 = (_Float16*)carve((size_t)MC * 1024 * 2);
    float*    hbar = (float*)carve((size_t)CB * 1024 * 4);

    const dim3 blk256(256);
    const dim3 rgrid((CB * 512) / 256);

    // ---- per-call weight prep ----------------------------------------------
    wsplit_t<<<dim3(4096 / 32, 512 / 32),  blk256, 0, stream>>>(W0, W0t, 512, 4096);
    wsplit_t<<<dim3(3072 / 32, 1024 / 32), blk256, 0, stream>>>(W1, W1t, 1024, 3072);
    wsplit_t<<<dim3(3072 / 32, 1024 / 32), blk256, 0, stream>>>(W2, W2t, 1024, 3072);

    for (int cb = 0; cb < BATCH / CB; ++cb) {
        const float* xc   = x   + (size_t)cb * CB * TSTEPS * IMG;
        float*       outc = out + (size_t)cb * CB * NCLASS;

        // layer 0: x->fp16, U = x @ W0 (N=4096, K=512); resid = U[:,3H:]
        esplit<<<dim3((MC * 512) / 256), blk256, 0, stream>>>(xc, x16, MC * 512);
        gemm_f16<<<dim3(4096 / 128, MC / 128), blk256, 0, stream>>>(x16, W0t, U, 4096, 512);
        sru_recur<<<rgrid, blk256, 0, stream>>>(U, 4096, U + 3 * HIDN, 4096,
            vc0, b0, hA16, nullptr);

        // layer 1: U = hA @ W1 (N=3072, K=1024); resid = hA (fp16)
        gemm_f16<<<dim3(3072 / 128, MC / 128), blk256, 0, stream>>>(hA16, W1t, U, 3072, 1024);
        sru_recur<<<rgrid, blk256, 0, stream>>>(U, 3072, hA16, HIDN,
            vc1, b1, hB16, nullptr);

        // layer 2: U = hB @ W2; resid = hB (fp16); emit hbar only
        gemm_f16<<<dim3(3072 / 128, MC / 128), blk256, 0, stream>>>(hB16, W2t, U, 3072, 1024);
        sru_recur<<<rgrid, blk256, 0, stream>>>(U, 3072, hB16, HIDN,
            vc2, b2, nullptr, hbar);

        // final FC on time-averaged h
        final_fc<<<dim3(CB), dim3(64), 0, stream>>>(hbar, fcw, fcb, outc);
    }
}

// Round 6
// 853.533 us; speedup vs baseline: 6.4589x; 1.0853x over previous
//
#include <hip/hip_runtime.h>
#include <math.h>

#define TSTEPS 12
#define BATCH  2048
#define IMG    512
#define HIDN   1024
#define NCLASS 51
#define SCALE_X 1.7320508075688772f      // sqrt(1 + 2*e^0) = sqrt(3)

typedef __attribute__((ext_vector_type(8))) _Float16 f16x8;
typedef __attribute__((ext_vector_type(2))) _Float16 f16x2;
typedef __attribute__((ext_vector_type(4))) float    f32x4;

__device__ __forceinline__ float sigf(float x) {
    return 1.f / (1.f + __expf(-x));
}

// ---------------------------------------------------------------------------
// Fused fp16 MFMA GEMM + SRU recurrence.
//   A fp16 row-major M x K, rows ordered (batch, t), t inner.
//   Bt: interleaved weight plane, row n = h*NCOMP + comp, length K
//       (so 32*NCOMP consecutive plane rows = all comps of 32 channels).
//   Block tile: BM=192 rows (16 whole batches) x BN=32*NCOMP cols.
//   K-loop: double-buffered global_load_lds staging, 4 waves in 2x2,
//   wave tile 96 x BN/2 via mfma_f32_16x16x32_f16.
//   Epilogue: acc -> LDS (fp16, unioned with staging), 12-step SRU
//   recurrence in-block; writes h fp16 (hout) and/or mean_t h (hbar).
//   resid: NCOMP==4 -> comp 3 of U; NCOMP==3 -> global fp16 [M x HIDN].
// ---------------------------------------------------------------------------
template<int NCOMP>
__global__ __launch_bounds__(256)
void gemm_sru(const _Float16* __restrict__ A, const _Float16* __restrict__ Bt,
              const _Float16* __restrict__ resid,
              const float* __restrict__ vc, const float* __restrict__ bias,
              _Float16* __restrict__ hout, float* __restrict__ hbar, int K) {
    constexpr int BM = 192, BN = 32 * NCOMP, HBN = BN / 2, NJ = NCOMP;
    constexpr int S_A = 2 * BM * 32;              // A staging halfs (2 bufs)
    constexpr int S_B = 2 * BN * 32;              // B staging halfs (2 bufs)
    constexpr int EPAD = BN + 8;
    constexpr int EPI = BM * EPAD;                // epilogue U tile halfs
    constexpr int TOT = (S_A + S_B) > EPI ? (S_A + S_B) : EPI;
    __shared__ _Float16 smem[TOT];

    const int tid  = threadIdx.x;
    const int lane = tid & 63;
    const int w    = tid >> 6;                    // wave 0..3
    const int bm   = blockIdx.y * BM;             // multiple of 12 (192=16*12)
    const int bn   = blockIdx.x * BN;

    // ---- staging assignment (wave-uniform) ---------------------------------
    const bool isA  = (w < 2);
    const _Float16* splane = isA ? A : Bt;
    const int srow0 = isA ? (bm + (w & 1) * 96) : (bn + (w & 1) * HBN);
    const int nrows = isA ? 96 : HBN;             // rows staged by this wave
    const int lrow  = lane >> 2;                  // 16 rows per instruction
    const int lcol  = (lane & 3) * 8;             // halfs; 16 B per lane

    const int wy = (w >> 1) * 96;                 // wave compute origin
    const int wx = (w & 1) * HBN;

    f32x4 acc[6][NJ];
    #pragma unroll
    for (int i = 0; i < 6; ++i)
        #pragma unroll
        for (int j = 0; j < NJ; ++j) acc[i][j] = (f32x4){0.f, 0.f, 0.f, 0.f};

    const int kq = (lane >> 4) * 8;               // fragment k-offset (halfs)
    const int mr = lane & 15;

    const _Float16* gbase = splane + (size_t)(srow0 + lrow) * K + lcol;

    auto stage = [&](int buf, int k0) {
        const _Float16* g = gbase + k0;
        _Float16* l = isA ? (smem + buf * BM * 32 + (w & 1) * (96 * 32))
                          : (smem + S_A + buf * BN * 32 + (w & 1) * (HBN * 32));
        for (int j = 0; j < nrows / 16; ++j)
            __builtin_amdgcn_global_load_lds(
                (const __attribute__((address_space(1))) unsigned int*)(g + (size_t)j * 16 * K),
                (__attribute__((address_space(3))) unsigned int*)(l + j * 512),
                16, 0, 0);
    };

    stage(0, 0);                                  // prologue prefetch

    int cur = 0;
    for (int k0 = 0; k0 < K; k0 += 32) {
        __syncthreads();                          // drains prev-iter prefetch
        if (k0 + 32 < K) stage(cur ^ 1, k0 + 32);

        const _Float16* la = smem + cur * BM * 32;
        const _Float16* lb = smem + S_A + cur * BN * 32;
        f16x8 a[6], b[NJ];
        #pragma unroll
        for (int i = 0; i < 6; ++i)
            a[i] = *(const f16x8*)&la[(wy + i * 16 + mr) * 32 + kq];
        #pragma unroll
        for (int j = 0; j < NJ; ++j)
            b[j] = *(const f16x8*)&lb[(wx + j * 16 + mr) * 32 + kq];
        #pragma unroll
        for (int i = 0; i < 6; ++i)
            #pragma unroll
            for (int j = 0; j < NJ; ++j)
                acc[i][j] = __builtin_amdgcn_mfma_f32_16x16x32_f16(a[i], b[j], acc[i][j], 0, 0, 0);
        cur ^= 1;
    }

    // ---- epilogue: acc -> LDS (fp16 U tile), then in-block recurrence ------
    __syncthreads();                              // staging LDS free for reuse
    {
        _Float16 (*uld)[EPAD] = (_Float16 (*)[EPAD])smem;
        const int r0 = (lane >> 4) << 2;
        #pragma unroll
        for (int i = 0; i < 6; ++i)
            #pragma unroll
            for (int j = 0; j < NJ; ++j)
                #pragma unroll
                for (int r = 0; r < 4; ++r)
                    uld[wy + i * 16 + r0 + r][wx + j * 16 + mr] =
                        (_Float16)acc[i][j][r];
    }
    __syncthreads();

    {
        _Float16 (*uld)[EPAD] = (_Float16 (*)[EPAD])smem;
        const int bl   = tid >> 4;                // local batch 0..15
        const int ch0  = (tid & 15) * 2;          // channel pair 0,2,..,30
        const int gcol = blockIdx.x * 32 + ch0;   // global channel
        const int gb   = bm / 12 + bl;            // global batch

        const float2 vf  = *(const float2*)&vc[gcol];
        const float2 vr  = *(const float2*)&vc[HIDN + gcol];
        const float2 bfv = *(const float2*)&bias[gcol];
        const float2 brv = *(const float2*)&bias[HIDN + gcol];

        float c0 = 0.f, c1 = 0.f, s0 = 0.f, s1 = 0.f;
        #pragma unroll
        for (int t = 0; t < TSTEPS; ++t) {
            const int row = bl * 12 + t;
            const float u0a = (float)uld[row][(ch0    ) * NCOMP + 0];
            const float u1a = (float)uld[row][(ch0    ) * NCOMP + 1];
            const float u2a = (float)uld[row][(ch0    ) * NCOMP + 2];
            const float u0b = (float)uld[row][(ch0 + 1) * NCOMP + 0];
            const float u1b = (float)uld[row][(ch0 + 1) * NCOMP + 1];
            const float u2b = (float)uld[row][(ch0 + 1) * NCOMP + 2];
            float xta, xtb;
            if (NCOMP == 4) {
                xta = (float)uld[row][(ch0    ) * 4 + 3];
                xtb = (float)uld[row][(ch0 + 1) * 4 + 3];
            } else {
                const f16x2 xv = *(const f16x2*)&resid[(size_t)(bm + row) * HIDN + gcol];
                xta = (float)xv[0]; xtb = (float)xv[1];
            }

            const float f0 = sigf(u1a + vf.x * c0 + bfv.x);
            c0 = f0 * c0 + (1.f - f0) * u0a;
            const float r0_ = sigf(u2a + vr.x * c0 + brv.x);
            const float th0 = 2.f * sigf(2.f * c0) - 1.f;
            const float hv0 = r0_ * th0 + (1.f - r0_) * xta * SCALE_X;

            const float f1 = sigf(u1b + vf.y * c1 + bfv.y);
            c1 = f1 * c1 + (1.f - f1) * u0b;
            const float r1_ = sigf(u2b + vr.y * c1 + brv.y);
            const float th1 = 2.f * sigf(2.f * c1) - 1.f;
            const float hv1 = r1_ * th1 + (1.f - r1_) * xtb * SCALE_X;

            if (hout) {
                f16x2 hv = { (_Float16)hv0, (_Float16)hv1 };
                *(f16x2*)&hout[(size_t)(bm + row) * HIDN + gcol] = hv;
            }
            s0 += hv0; s1 += hv1;
        }
        if (hbar) {
            float2 hb = make_float2(s0 * (1.f / TSTEPS), s1 * (1.f / TSTEPS));
            *(float2*)&hbar[(size_t)gb * HIDN + gcol] = hb;
        }
    }
}

// ---------------------------------------------------------------------------
// Weight transpose + fp16 + channel-interleave:
//   W (K x N fp32), N = NCOMP*1024, col n = comp*1024 + h
//   -> plane row (h*NCOMP + comp), length K, fp16.
// ---------------------------------------------------------------------------
__global__ __launch_bounds__(256)
void wsplit_t(const float* __restrict__ W, _Float16* __restrict__ Wt,
              int K, int N, int ncomp) {
    __shared__ float tile[32][33];
    const int bn = blockIdx.x * 32;
    const int bk = blockIdx.y * 32;
    const int tx = threadIdx.x & 31;
    const int ty = threadIdx.x >> 5;              // 0..7
    #pragma unroll
    for (int i = 0; i < 32; i += 8)
        tile[ty + i][tx] = W[(size_t)(bk + ty + i) * N + bn + tx];
    __syncthreads();
    #pragma unroll
    for (int i = 0; i < 32; i += 8) {
        const int n = bn + ty + i;
        const int nr = (n & 1023) * ncomp + (n >> 10);   // h*ncomp + comp
        Wt[(size_t)nr * K + bk + tx] = (_Float16)tile[tx][ty + i];
    }
}

// elementwise fp32 -> fp16 convert (for x chunks)
__global__ __launch_bounds__(256)
void esplit(const float* __restrict__ src, _Float16* __restrict__ dst, int n) {
    int i = blockIdx.x * 256 + threadIdx.x;
    if (i < n) dst[i] = (_Float16)src[i];
}

// ---------------------------------------------------------------------------
// Final FC on time-averaged h: out[b,c] = hbar[b,:] . fc_w[:,c] + fc_b[c]
// ---------------------------------------------------------------------------
__global__ __launch_bounds__(64)
void final_fc(const float* __restrict__ hbar, const float* __restrict__ fcw,
              const float* __restrict__ fcb, float* __restrict__ out) {
    __shared__ float hrow[HIDN];
    const int b = blockIdx.x;
    for (int i = threadIdx.x; i < HIDN; i += 64)
        hrow[i] = hbar[(size_t)b * HIDN + i];
    __syncthreads();

    const int c = threadIdx.x;
    if (c < NCLASS) {
        float acc = fcb[c];
        #pragma unroll 8
        for (int k = 0; k < HIDN; ++k)
            acc = fmaf(hrow[k], fcw[(size_t)k * NCLASS + c], acc);
        out[(size_t)b * NCLASS + c] = acc;
    }
}

// ---------------------------------------------------------------------------
extern "C" void kernel_launch(void* const* d_in, const int* in_sizes, int n_in,
                              void* d_out, int out_size, void* d_ws, size_t ws_size,
                              hipStream_t stream) {
    const float* x   = (const float*)d_in[0];   // (B, T, IMG)
    const float* W0  = (const float*)d_in[1];   // (IMG, 4H)
    const float* W1  = (const float*)d_in[2];   // (H, 3H)
    const float* W2  = (const float*)d_in[3];   // (H, 3H)
    const float* vc0 = (const float*)d_in[4];
    const float* vc1 = (const float*)d_in[5];
    const float* vc2 = (const float*)d_in[6];
    const float* b0  = (const float*)d_in[7];
    const float* b1  = (const float*)d_in[8];
    const float* b2  = (const float*)d_in[9];
    const float* fcw = (const float*)d_in[10];  // (H, NCLASS)
    const float* fcb = (const float*)d_in[11];
    float* out = (float*)d_out;                 // (B, NCLASS)

    // ---- workspace carve-up -------------------------------------------------
    char* ws = (char*)d_ws;
    size_t off = 0;
    auto carve = [&](size_t bytes) { char* p = ws + off; off = (off + bytes + 255) & ~255ull; return p; };

    _Float16* W0t = (_Float16*)carve((size_t)4096 * 512 * 2);   // 4 MB
    _Float16* W1t = (_Float16*)carve((size_t)3072 * 1024 * 2);  // 6 MB
    _Float16* W2t = (_Float16*)carve((size_t)3072 * 1024 * 2);  // 6 MB
    const size_t W_BYTES = off;

    // per-batch arena: x16(12*512*2) + hA16(12*1024*2) + hB16 + hbar(1024*4)
    const size_t PER_B = 12ull * 512 * 2 + 2ull * 12 * 1024 * 2 + 1024ull * 4 + 1024;
    int CB = 32;                                 // all ladder values are mult of 16
    if      (W_BYTES + 2048ull * PER_B <= ws_size) CB = 2048;
    else if (W_BYTES + 1024ull * PER_B <= ws_size) CB = 1024;
    else if (W_BYTES +  512ull * PER_B <= ws_size) CB = 512;
    else if (W_BYTES +  256ull * PER_B <= ws_size) CB = 256;
    else if (W_BYTES +  128ull * PER_B <= ws_size) CB = 128;
    else if (W_BYTES +   64ull * PER_B <= ws_size) CB = 64;
    const int MC = CB * TSTEPS;                  // rows; CB%16==0 -> 192 | MC

    _Float16* x16  = (_Float16*)carve((size_t)MC * 512 * 2);
    _Float16* hA16 = (_Float16*)carve((size_t)MC * 1024 * 2);
    _Float16* hB16 = (_Float16*)carve((size_t)MC * 1024 * 2);
    float*    hbar = (float*)carve((size_t)CB * 1024 * 4);

    const dim3 blk256(256);

    // ---- per-call weight prep (interleaved fp16 planes) --------------------
    wsplit_t<<<dim3(4096 / 32, 512 / 32),  blk256, 0, stream>>>(W0, W0t, 512, 4096, 4);
    wsplit_t<<<dim3(3072 / 32, 1024 / 32), blk256, 0, stream>>>(W1, W1t, 1024, 3072, 3);
    wsplit_t<<<dim3(3072 / 32, 1024 / 32), blk256, 0, stream>>>(W2, W2t, 1024, 3072, 3);

    for (int cb = 0; cb < BATCH / CB; ++cb) {
        const float* xc   = x   + (size_t)cb * CB * TSTEPS * IMG;
        float*       outc = out + (size_t)cb * CB * NCLASS;

        // layer 0: x->fp16; fused GEMM(K=512, NCOMP=4) + recurrence -> hA16
        esplit<<<dim3((MC * 512) / 256), blk256, 0, stream>>>(xc, x16, MC * 512);
        gemm_sru<4><<<dim3(4096 / 128, MC / 192), blk256, 0, stream>>>(
            x16, W0t, nullptr, vc0, b0, hA16, nullptr, 512);

        // layer 1: fused GEMM(K=1024, NCOMP=3) + recurrence -> hB16
        gemm_sru<3><<<dim3(3072 / 96, MC / 192), blk256, 0, stream>>>(
            hA16, W1t, hA16, vc1, b1, hB16, nullptr, 1024);

        // layer 2: fused; emit hbar only
        gemm_sru<3><<<dim3(3072 / 96, MC / 192), blk256, 0, stream>>>(
            hB16, W2t, hB16, vc2, b2, nullptr, hbar, 1024);

        // final FC on time-averaged h
        final_fc<<<dim3(CB), dim3(64), 0, stream>>>(hbar, fcw, fcb, outc);
    }
}